// Round 8
// baseline (110.578 us; speedup 1.0000x reference)
//
#include <hip/hip_runtime.h>

// ante[e, i*3+j] = exp(-2*(x1 - c_i)^2) * exp(-2*(x2 - c_j)^2)
// x1 = feat[dst][0] - feat[src][0], x2 = feat[dst][1] - feat[src][1]
//
// R8: software-pipelined persistent blocks. Gather floor measured ~74us
// (R6 K1); fused R4 = 97us = gather + ~23us unoverlapped streaming.
// Grid = 2048 (8 blocks/CU), each block walks tiles (512 edges) with a
// rolling pipeline: gathers for tile t+G issued before compute/store of
// tile t (indices prefetched one iteration ahead of that). Two unrolled
// A/B stages avoid register copies. LDS 18KB, VGPR-lean epilogue.

#define TPB 256

typedef float  f2 __attribute__((ext_vector_type(2)));
typedef float  f4 __attribute__((ext_vector_type(4)));
typedef int    i2 __attribute__((ext_vector_type(2)));

__device__ __forceinline__ void load_idx(const int* __restrict__ esrc,
                                         const int* __restrict__ edst,
                                         int t, int tid, i2& s, i2& d) {
    const size_t base = (size_t)t * (TPB * 2) + 2 * tid;
    s = __builtin_nontemporal_load(reinterpret_cast<const i2*>(esrc + base));
    d = __builtin_nontemporal_load(reinterpret_cast<const i2*>(edst + base));
}

__device__ __forceinline__ void gath(const float* __restrict__ feat,
                                     const i2 s, const i2 d, f2 g[4]) {
    g[0] = *reinterpret_cast<const f2*>(feat + (size_t)s.x * 8);
    g[1] = *reinterpret_cast<const f2*>(feat + (size_t)d.x * 8);
    g[2] = *reinterpret_cast<const f2*>(feat + (size_t)s.y * 8);
    g[3] = *reinterpret_cast<const f2*>(feat + (size_t)d.y * 8);
}

__device__ __forceinline__ void memb(float x, float m[3]) {
    const float a = x + 1.0f, c = x - 1.0f;
    m[0] = __expf(-2.0f * a * a);
    m[1] = __expf(-2.0f * x * x);
    m[2] = __expf(-2.0f * c * c);
}

__device__ __forceinline__ void compute_store(const f2 g[4], int t, int tid,
                                              float* lds, float* __restrict__ out) {
    float m1a[3], m2a[3], m1b[3], m2b[3];
    memb(g[1].x - g[0].x, m1a);
    memb(g[1].y - g[0].y, m2a);
    memb(g[3].x - g[2].x, m1b);
    memb(g[3].y - g[2].y, m2b);

    __syncthreads();   // prior tile's LDS reads done
    f2* my2 = reinterpret_cast<f2*>(lds) + tid * 9;
    f2 v;
    v.x = m1a[0] * m2a[0]; v.y = m1a[0] * m2a[1]; my2[0] = v;
    v.x = m1a[0] * m2a[2]; v.y = m1a[1] * m2a[0]; my2[1] = v;
    v.x = m1a[1] * m2a[1]; v.y = m1a[1] * m2a[2]; my2[2] = v;
    v.x = m1a[2] * m2a[0]; v.y = m1a[2] * m2a[1]; my2[3] = v;
    v.x = m1a[2] * m2a[2]; v.y = m1b[0] * m2b[0]; my2[4] = v;
    v.x = m1b[0] * m2b[1]; v.y = m1b[0] * m2b[2]; my2[5] = v;
    v.x = m1b[1] * m2b[0]; v.y = m1b[1] * m2b[1]; my2[6] = v;
    v.x = m1b[1] * m2b[2]; v.y = m1b[2] * m2b[0]; my2[7] = v;
    v.x = m1b[2] * m2b[1]; v.y = m1b[2] * m2b[2]; my2[8] = v;
    __syncthreads();

    const f4* lds4 = reinterpret_cast<const f4*>(lds);
    f4* out4 = reinterpret_cast<f4*>(out);
    const size_t tf4 = (size_t)t * (TPB * 9 / 2);   // 1152 f4 per tile
#pragma unroll
    for (int k = 0; k < 5; ++k) {
        const int f = k * TPB + tid;
        if (f < TPB * 9 / 2)
            __builtin_nontemporal_store(lds4[f], out4 + tf4 + f);
    }
}

__global__ __launch_bounds__(TPB, 8) void ante_kernel(
    const float* __restrict__ feat,
    const int*   __restrict__ esrc,
    const int*   __restrict__ edst,
    float*       __restrict__ out,
    int ntiles)
{
    __shared__ float lds[TPB * 18];
    const int tid = threadIdx.x;
    const int G   = gridDim.x;

    int t = blockIdx.x;
    if (t >= ntiles) return;

    i2 sA, dA, sB, dB;
    f2 gA[4], gB[4];

    // prologue: tile t fully issued; idx for t+G in flight
    load_idx(esrc, edst, t, tid, sA, dA);
    gath(feat, sA, dA, gA);
    int t2 = t + G;
    bool vB = t2 < ntiles;
    if (vB) load_idx(esrc, edst, t2, tid, sB, dB);

    for (;;) {
        // stage A: process t (gA); prefetch gathers(t2) via B idx; idx(t3)->A
        if (vB) gath(feat, sB, dB, gB);
        int t3 = t2 + G; bool v3 = t3 < ntiles;
        if (v3) load_idx(esrc, edst, t3, tid, sA, dA);
        compute_store(gA, t, tid, lds, out);
        if (!vB) break;
        t = t2; t2 = t3; vB = v3;

        // stage B: process t (gB); prefetch gathers(t2) via A idx; idx(t3)->B
        if (vB) gath(feat, sA, dA, gA);
        t3 = t2 + G; v3 = t3 < ntiles;
        if (v3) load_idx(esrc, edst, t3, tid, sB, dB);
        compute_store(gB, t, tid, lds, out);
        if (!vB) break;
        t = t2; t2 = t3; vB = v3;
    }
}

extern "C" void kernel_launch(void* const* d_in, const int* in_sizes, int n_in,
                              void* d_out, int out_size, void* d_ws, size_t ws_size,
                              hipStream_t stream) {
    const float* feat = (const float*)d_in[0];
    const int*   esrc = (const int*)d_in[1];
    const int*   edst = (const int*)d_in[2];
    float* out = (float*)d_out;

    const int E = in_sizes[1];           // 6,400,000
    const int ntiles = E / (TPB * 2);    // 12,500 (exact)
    const int grid = (ntiles < 2048) ? ntiles : 2048;  // 8 blocks/CU
    ante_kernel<<<grid, TPB, 0, stream>>>(feat, esrc, edst, out, ntiles);
}

// Round 9
// 107.593 us; speedup vs baseline: 1.0277x; 1.0277x over previous
//
#include <hip/hip_runtime.h>

// ante[e, i*3+j] = exp(-2*(x1 - c_i)^2) * exp(-2*(x2 - c_j)^2)
// x1 = feat[dst][0] - feat[src][0], x2 = feat[dst][1] - feat[src][1]
//
// R9: barrier-free wave-local transpose. R2-R8: only store contiguity ever
// helped; occupancy/footprint/MLP/pipelining all nil or negative. Last
// structural suspect: the 2 block-wide barriers convoy 4 waves per block
// (fast waves can't store until slowest wave's gathers land -> TA gather
// queue drains in bursts). Fix: each wave transposes through its OWN 4.6KB
// LDS slice -- intra-wave exchange only, so a s_waitcnt lgkmcnt(0) replaces
// __syncthreads entirely. Every wave free-runs.
// Geometry = R4: 2 edges/thread, 18.4KB/block, 8 blocks/CU, bank-floor LDS,
// contiguous 1KB-per-instruction f4 stores.

#define TPB 256

typedef float  f2 __attribute__((ext_vector_type(2)));
typedef float  f4 __attribute__((ext_vector_type(4)));
typedef int    i2 __attribute__((ext_vector_type(2)));

__global__ __launch_bounds__(TPB, 8) void ante_kernel(
    const float* __restrict__ feat,
    const int*   __restrict__ esrc,
    const int*   __restrict__ edst,
    float*       __restrict__ out)
{
    __shared__ float lds[4][18 * 64];   // 4.6KB per wave, 18.4KB/block
    const int tid  = threadIdx.x;
    const int wid  = tid >> 6;
    const int lane = tid & 63;
    const size_t t = (size_t)blockIdx.x * TPB + tid;   // 2-edge group id

    // coalesced index loads (8B/lane)
    const i2 s2 = __builtin_nontemporal_load(reinterpret_cast<const i2*>(esrc) + t);
    const i2 d2 = __builtin_nontemporal_load(reinterpret_cast<const i2*>(edst) + t);

    // 4 scattered gathers, issued back-to-back
    const f2 fs0 = *reinterpret_cast<const f2*>(feat + (size_t)s2.x * 8);
    const f2 fd0 = *reinterpret_cast<const f2*>(feat + (size_t)d2.x * 8);
    const f2 fs1 = *reinterpret_cast<const f2*>(feat + (size_t)s2.y * 8);
    const f2 fd1 = *reinterpret_cast<const f2*>(feat + (size_t)d2.y * 8);

    float m1a[3], m2a[3], m1b[3], m2b[3];
    {
        const float x = fd0.x - fs0.x, a = x + 1.0f, c = x - 1.0f;
        m1a[0] = __expf(-2.0f * a * a); m1a[1] = __expf(-2.0f * x * x); m1a[2] = __expf(-2.0f * c * c);
    }
    {
        const float x = fd0.y - fs0.y, a = x + 1.0f, c = x - 1.0f;
        m2a[0] = __expf(-2.0f * a * a); m2a[1] = __expf(-2.0f * x * x); m2a[2] = __expf(-2.0f * c * c);
    }
    {
        const float x = fd1.x - fs1.x, a = x + 1.0f, c = x - 1.0f;
        m1b[0] = __expf(-2.0f * a * a); m1b[1] = __expf(-2.0f * x * x); m1b[2] = __expf(-2.0f * c * c);
    }
    {
        const float x = fd1.y - fs1.y, a = x + 1.0f, c = x - 1.0f;
        m2b[0] = __expf(-2.0f * a * a); m2b[1] = __expf(-2.0f * x * x); m2b[2] = __expf(-2.0f * c * c);
    }

    // 9 x ds_write_b64 into this wave's slice (bank-floor pattern)
    f2* my2 = reinterpret_cast<f2*>(&lds[wid][lane * 18]);
    f2 v;
    v.x = m1a[0] * m2a[0]; v.y = m1a[0] * m2a[1]; my2[0] = v;
    v.x = m1a[0] * m2a[2]; v.y = m1a[1] * m2a[0]; my2[1] = v;
    v.x = m1a[1] * m2a[1]; v.y = m1a[1] * m2a[2]; my2[2] = v;
    v.x = m1a[2] * m2a[0]; v.y = m1a[2] * m2a[1]; my2[3] = v;
    v.x = m1a[2] * m2a[2]; v.y = m1b[0] * m2b[0]; my2[4] = v;
    v.x = m1b[0] * m2b[1]; v.y = m1b[0] * m2b[2]; my2[5] = v;
    v.x = m1b[1] * m2b[0]; v.y = m1b[1] * m2b[1]; my2[6] = v;
    v.x = m1b[1] * m2b[2]; v.y = m1b[2] * m2b[0]; my2[7] = v;
    v.x = m1b[2] * m2b[1]; v.y = m1b[2] * m2b[2]; my2[8] = v;

    // Intra-wave visibility: all 64 lanes' ds_writes complete at lgkmcnt(0).
    // memory clobber pins the following ds_reads; sched_barrier is insurance
    // against the scheduler hoisting them (rule #18).
    asm volatile("s_waitcnt lgkmcnt(0)" ::: "memory");
    __builtin_amdgcn_sched_barrier(0);

    // Wave-local store: wave covers 128 edges -> 288 contiguous f4.
    // Slice float f == global output float (wave_edge0*9 + f).
    const f4* lds4 = reinterpret_cast<const f4*>(&lds[wid][0]);
    f4* out4 = reinterpret_cast<f4*>(out);
    const size_t ob = (size_t)blockIdx.x * (TPB * 9 / 2) + (size_t)wid * 288;
#pragma unroll
    for (int k = 0; k < 5; ++k) {
        const int f = k * 64 + lane;
        if (f < 288)
            __builtin_nontemporal_store(lds4[f], out4 + ob + f);
    }
}

extern "C" void kernel_launch(void* const* d_in, const int* in_sizes, int n_in,
                              void* d_out, int out_size, void* d_ws, size_t ws_size,
                              hipStream_t stream) {
    const float* feat = (const float*)d_in[0];
    const int*   esrc = (const int*)d_in[1];
    const int*   edst = (const int*)d_in[2];
    float* out = (float*)d_out;

    const int E  = in_sizes[1];          // 6,400,000
    const int e2 = E / 2;                // 3,200,000 2-edge groups
    const int grid = e2 / TPB;           // 12,500 exact
    ante_kernel<<<grid, TPB, 0, stream>>>(feat, esrc, edst, out);
}